// Round 8
// baseline (581.076 us; speedup 1.0000x reference)
//
#include <hip/hip_runtime.h>
#include <math.h>

// ---------------------------------------------------------------------------
// ResCNN_ASP_SpeakerEncoder — v7: dconv TT=128 + frag-order loads combined;
// sm_pass_c fused into asp_fused via chunk-local-max rescale (logits never
// written to HBM).
// ---------------------------------------------------------------------------

constexpr int B_  = 64;
constexpr int T_  = 3000;
constexpr int NB_ = 257;   // NBINS
constexpr int R_  = B_ * T_;           // 192000 rows
constexpr int NCH = 24;                // softmax T-chunks (24 x 128)
constexpr int CHL = 128;

// workspace layout (float offsets)
constexpr size_t OFF_BS    = 0;                            // sorted binpoints (82)
constexpr size_t OFF_WEFF  = 128;                          // ushort hi[64*256]+lo (frag order)
constexpr size_t OFF_WTAIL = OFF_WEFF + 20480;             // fp32 [64]
constexpr size_t OFF_W1    = OFF_WTAIL + 128;              // ushort hi[3*128*64]+lo
constexpr size_t OFF_W2    = OFF_W1  + 3*64*128;           // ushort hi[3*128*128]+lo
constexpr size_t OFF_W3    = OFF_W2  + 3*128*128;
constexpr size_t OFF_WA1   = OFF_W3  + 3*128*128;          // ushort hi[64*128]+lo
constexpr size_t OFF_WA2   = OFF_WA1 + 8192;               // ushort hi[128*64]+lo
constexpr size_t SZ_P      = (size_t)B_*NCH*128;
constexpr size_t OFF_PM    = OFF_WA2 + 8192;
constexpr size_t OFF_PS    = OFF_PM  + SZ_P;
constexpr size_t OFF_MS    = OFF_PS  + SZ_P;               // [B][128]
constexpr size_t OFF_SS    = OFF_MS  + (size_t)B_*128;
constexpr size_t OFF_PCM   = OFF_SS  + (size_t)B_*128;
constexpr size_t OFF_PCQ   = OFF_PCM + SZ_P;
constexpr size_t OFF_H     = OFF_PCQ + SZ_P;               // [R][64]  (h)
constexpr size_t OFF_A     = OFF_H   + (size_t)R_*64;      // [R][128] (i1, later i3)
constexpr size_t OFF_BB    = OFF_A   + (size_t)R_*128;     // [R][128] (unused now)

typedef __attribute__((ext_vector_type(8))) short  bf16x8;
typedef __attribute__((ext_vector_type(4))) float  f32x4;
typedef __attribute__((ext_vector_type(4), aligned(4))) float float4a;  // 4B-aligned ok
typedef unsigned short ushort_t;

__device__ inline ushort_t f2bf(float f) {                // RNE f32->bf16
    unsigned u = __float_as_uint(f);
    unsigned r = u + 0x7FFFu + ((u >> 16) & 1u);
    return (ushort_t)(r >> 16);
}
__device__ inline float bf2f(ushort_t h) {
    return __uint_as_float(((unsigned)h) << 16);
}

// hw-packed split: v -> bf16 hi pair + bf16 lo pair (RNE), 6 insts per 4 elems
__device__ inline void split_pack(float x, float y, float z, float w,
                                  uint2 &ph, uint2 &pl) {
    unsigned hx, hy;
    asm("v_cvt_pk_bf16_f32 %0, %1, %2" : "=v"(hx) : "v"(x), "v"(y));
    asm("v_cvt_pk_bf16_f32 %0, %1, %2" : "=v"(hy) : "v"(z), "v"(w));
    float l0 = x - __uint_as_float(hx << 16);
    float l1 = y - __uint_as_float(hx & 0xFFFF0000u);
    float l2 = z - __uint_as_float(hy << 16);
    float l3 = w - __uint_as_float(hy & 0xFFFF0000u);
    unsigned lx, ly;
    asm("v_cvt_pk_bf16_f32 %0, %1, %2" : "=v"(lx) : "v"(l0), "v"(l1));
    asm("v_cvt_pk_bf16_f32 %0, %1, %2" : "=v"(ly) : "v"(l2), "v"(l3));
    ph.x = hx; ph.y = hy; pl.x = lx; pl.y = ly;
}

// ---------------------------------------------------------------------------
__global__ void sort_kernel(const float* __restrict__ bp, float* __restrict__ bs) {
    if (threadIdx.x == 0) {
        float tmp[82];
        for (int i = 0; i < 82; ++i) tmp[i] = bp[i];
        for (int i = 1; i < 82; ++i) {
            float key = tmp[i];
            int j = i - 1;
            while (j >= 0 && tmp[j] > key) { tmp[j+1] = tmp[j]; --j; }
            tmp[j+1] = key;
        }
        for (int i = 0; i < 82; ++i) bs[i] = tmp[i];
    }
}

// Fragment-order packing (B: lane&15=col, lane>>4=k-octet; A: lane&15=row).
__global__ void prep_kernel(const float* __restrict__ bs, const float* __restrict__ wl1,
                            const float* __restrict__ wc1, const float* __restrict__ wc2,
                            const float* __restrict__ wc3, const float* __restrict__ wa1,
                            const float* __restrict__ wa2,
                            ushort_t* __restrict__ weh, ushort_t* __restrict__ wel,
                            float* __restrict__ wtail,
                            ushort_t* __restrict__ w1h, ushort_t* __restrict__ w1l,
                            ushort_t* __restrict__ w2h, ushort_t* __restrict__ w2l,
                            ushort_t* __restrict__ w3h, ushort_t* __restrict__ w3l,
                            ushort_t* __restrict__ wa1h, ushort_t* __restrict__ wa1l,
                            ushort_t* __restrict__ wa2h, ushort_t* __restrict__ wa2l) {
    int gid = blockIdx.x * 256 + threadIdx.x;
    if (gid < 64*320) {                            // Weff[o][f]
        int o = gid / 320, f = gid % 320;
        if (f > 256) return;
        float acc = 0.0f;
        if (f == 0) acc = wl1[o*80];               // filt[:,:,0] = x[:,:,0]
        else {
            for (int n = 1; n < 79; ++n) {         // fb rows 1..78 (row 79 zero)
                float bn = bs[n], bn1 = bs[n+1], bn2 = bs[n+2];
                int ibn  = (int)floorf(bn);
                int ibn1 = (int)floorf(bn1);
                int ibn2 = (int)floorf(bn2);
                float fbv = 0.0f;
                if (f >= ibn && f < ibn1) {
                    float d = (bn1-bn)*(bn1-bn);
                    fbv = ((float)f - bn) / (d > 0.0f ? d : 1.0f);
                } else if (f >= ibn1 && f < ibn2) {
                    float d = (bn2-bn1)*(bn2-bn1);
                    fbv = (bn2 - (float)f) / (d > 0.0f ? d : 1.0f);
                }
                acc += wl1[o*80 + n] * fbv;
            }
        }
        if (f == 256) { wtail[o] = acc; return; }  // fp32 rank-1 tail column
        int kc = f >> 5, lane = ((f & 31) >> 3)*16 + (o & 15), e = f & 7;
        size_t dst = (((size_t)kc*4 + (o >> 4))*64 + lane)*8 + e;
        ushort_t h = f2bf(acc);
        weh[dst] = h; wel[dst] = f2bf(acc - bf2f(h));
        return;
    }
    gid -= 64*320;
    if (gid < 3*128*64) {                          // conv1: [k][c][ci=64]
        int k = gid / (128*64), rem = gid % (128*64);
        int c = rem >> 6, ci = rem & 63;
        float v = wc1[(c*64 + ci)*3 + k];
        int lane = ((ci & 31) >> 3)*16 + (c & 15), e = ci & 7;
        size_t dst = ((((size_t)k*2 + (ci >> 5))*8 + (c >> 4))*64 + lane)*8 + e;
        ushort_t h = f2bf(v);
        w1h[dst] = h; w1l[dst] = f2bf(v - bf2f(h));
        return;
    }
    gid -= 3*128*64;
    if (gid < 3*128*128) {                         // conv2: [k][c][ci=128]
        int k = gid / (128*128), rem = gid % (128*128);
        int c = rem >> 7, ci = rem & 127;
        float v = wc2[(c*128 + ci)*3 + k];
        int lane = ((ci & 31) >> 3)*16 + (c & 15), e = ci & 7;
        size_t dst = ((((size_t)k*4 + (ci >> 5))*8 + (c >> 4))*64 + lane)*8 + e;
        ushort_t h = f2bf(v);
        w2h[dst] = h; w2l[dst] = f2bf(v - bf2f(h));
        return;
    }
    gid -= 3*128*128;
    if (gid < 3*128*128) {                         // conv3
        int k = gid / (128*128), rem = gid % (128*128);
        int c = rem >> 7, ci = rem & 127;
        float v = wc3[(c*128 + ci)*3 + k];
        int lane = ((ci & 31) >> 3)*16 + (c & 15), e = ci & 7;
        size_t dst = ((((size_t)k*4 + (ci >> 5))*8 + (c >> 4))*64 + lane)*8 + e;
        ushort_t h = f2bf(v);
        w3h[dst] = h; w3l[dst] = f2bf(v - bf2f(h));
        return;
    }
    gid -= 3*128*128;
    if (gid < 64*128) {                            // wa1 [c=64][ci=128]
        int c = gid >> 7, ci = gid & 127;
        float v = wa1[gid];
        int lane = ((ci & 31) >> 3)*16 + (c & 15), e = ci & 7;
        size_t dst = (((size_t)(ci >> 5)*4 + (c >> 4))*64 + lane)*8 + e;
        ushort_t h = f2bf(v);
        wa1h[dst] = h; wa1l[dst] = f2bf(v - bf2f(h));
        return;
    }
    gid -= 64*128;
    if (gid < 128*64) {                            // wa2 [n=128][ci=64] (A operand)
        int n = gid >> 6, ci = gid & 63;
        float v = wa2[gid];
        int lane = ((ci & 31) >> 3)*16 + (n & 15), e = ci & 7;
        size_t dst = (((size_t)(ci >> 5)*8 + (n >> 4))*64 + lane)*8 + e;
        ushort_t h = f2bf(v);
        wa2h[dst] = h; wa2l[dst] = f2bf(v - bf2f(h));
        return;
    }
}

// ---------------------------------------------------------------------------
// lin1: h[t][c] = relu( x[t][:257] . Weff[c][:] + b[c] ).
__launch_bounds__(256)
__global__ void lin1_mfma(const float* __restrict__ X,
                          const ushort_t* __restrict__ Wh, const ushort_t* __restrict__ Wl,
                          const float* __restrict__ wtail,
                          const float* __restrict__ bias, float* __restrict__ H) {
    __shared__ __align__(16) ushort_t ash[128*64];
    __shared__ __align__(16) ushort_t asl[128*64];
    __shared__ float xs[128];
    __shared__ float wts[64];
    const int tid  = threadIdx.x;
    const int lane = tid & 63;
    const int wid  = tid >> 6;
    const int wy   = wid >> 1, wx = wid & 1;
    const int l16  = lane & 15, l4 = lane >> 4;
    const int r0   = blockIdx.x * 128;

    if (tid < 128)       xs[tid] = X[(size_t)(r0 + tid)*NB_ + 256];
    else if (tid < 192)  wts[tid - 128] = wtail[tid - 128];

#define LIN1_LOAD(dst, k0)                                            \
    _Pragma("unroll")                                                 \
    for (int i = 0; i < 8; ++i) {                                     \
        int q = tid + i*256; int r = q >> 4, cc = (q & 15) << 2;      \
        dst[i] = *(const float4a*)(X + (size_t)(r0 + r)*NB_ + (k0) + cc); \
    }
#define LIN1_CW(src)                                                  \
    _Pragma("unroll")                                                 \
    for (int i = 0; i < 8; ++i) {                                     \
        int q = tid + i*256; int r = q >> 4, cc = (q & 15) << 2;      \
        uint2 ph, pl;                                                 \
        split_pack(src[i].x, src[i].y, src[i].z, src[i].w, ph, pl);   \
        unsigned byte = ((unsigned)(r*64 + cc))*2u ^ ((unsigned)((r & 7) << 4)); \
        *(uint2*)((char*)ash + byte) = ph;                            \
        *(uint2*)((char*)asl + byte) = pl;                            \
    }

    float4a bufA[8], bufB[8];
    LIN1_LOAD(bufA, 0);

    f32x4 acc[4][2];
    const f32x4 z = {0.f,0.f,0.f,0.f};
#pragma unroll
    for (int m = 0; m < 4; ++m) { acc[m][0] = z; acc[m][1] = z; }

#pragma unroll
    for (int ck = 0; ck < 4; ++ck) {
        const float4a* cur = (ck & 1) ? bufB : bufA;
        float4a*       nxt = (ck & 1) ? bufA : bufB;
        if (ck < 3) LIN1_LOAD(nxt, (ck + 1)*64);
        LIN1_CW(cur);
        __syncthreads();
#pragma unroll
        for (int kk = 0; kk < 64; kk += 32) {
            bf16x8 bh[2], bl[2];
#pragma unroll
            for (int n = 0; n < 2; ++n) {          // frag-order: coalesced
                size_t off = (((size_t)(ck*2 + (kk >> 5))*4 + wx*2 + n)*64 + lane)*8;
                bh[n] = *(const bf16x8*)(Wh + off);
                bl[n] = *(const bf16x8*)(Wl + off);
            }
            bf16x8 fh[4], fl[4];
#pragma unroll
            for (int m = 0; m < 4; ++m) {
                int r = wy*64 + m*16 + l16;
                unsigned byte = ((unsigned)(r*64 + kk + l4*8))*2u ^ ((unsigned)((r & 7) << 4));
                fh[m] = *(const bf16x8*)((const char*)ash + byte);
                fl[m] = *(const bf16x8*)((const char*)asl + byte);
            }
#pragma unroll
            for (int m = 0; m < 4; ++m)
#pragma unroll
                for (int n = 0; n < 2; ++n) {
                    acc[m][n] = __builtin_amdgcn_mfma_f32_16x16x32_bf16(fh[m], bh[n], acc[m][n], 0, 0, 0);
                    acc[m][n] = __builtin_amdgcn_mfma_f32_16x16x32_bf16(fh[m], bl[n], acc[m][n], 0, 0, 0);
                    acc[m][n] = __builtin_amdgcn_mfma_f32_16x16x32_bf16(fl[m], bh[n], acc[m][n], 0, 0, 0);
                }
        }
        __syncthreads();
    }
#undef LIN1_LOAD
#undef LIN1_CW

#pragma unroll
    for (int m = 0; m < 4; ++m)
#pragma unroll
        for (int n = 0; n < 2; ++n) {
            int c = wx*32 + n*16 + l16;
            float bv = bias[c];
            float wc = wts[c];
            int rbl = wy*64 + m*16 + l4*4;
#pragma unroll
            for (int rg = 0; rg < 4; ++rg) {
                int rl = rbl + rg;
                float v = acc[m][n][rg] + bv + xs[rl]*wc;   // fp32 k=256 tail
                H[(size_t)(r0 + rl)*64 + c] = fmaxf(v, 0.0f);
            }
        }
}

// ---------------------------------------------------------------------------
// Dilated conv (K=3) via split-bf16 MFMA. TT=128 + frag-order weight loads.
template<int CIN, int DIL, int RES>
__launch_bounds__(256)
__global__ void dconv_mfma(const float* __restrict__ X,
                           const ushort_t* __restrict__ Wh,
                           const ushort_t* __restrict__ Wl,
                           const float* __restrict__ bias, float* __restrict__ Y) {
    constexpr int TT = 128;
    constexpr int HS = TT + 2*DIL;
    constexpr int NCHK = CIN/32;
    __shared__ __align__(16) ushort_t hsh[HS*CIN];
    __shared__ __align__(16) ushort_t hsl[HS*CIN];

    const int tid  = threadIdx.x;
    const int lane = tid & 63;
    const int wid  = tid >> 6;
    const int wy   = wid >> 1;            // rows wy*64 + m*16
    const int wx   = wid & 1;             // cols wx*64 + n*16
    const int l16  = lane & 15;
    const int l4   = lane >> 4;
    const int t0   = blockIdx.x * TT;
    const int b    = blockIdx.y;

    for (int idx = tid; idx < HS*CIN/4; idx += 256) {
        int e  = idx << 2;
        int r  = e / CIN, ci = e % CIN;
        int t  = t0 - DIL + r;
        float4 v = make_float4(0.f, 0.f, 0.f, 0.f);
        if (t >= 0 && t < T_) v = *(const float4*)&X[((size_t)b*T_ + t)*CIN + ci];
        uint2 ph, pl;
        split_pack(v.x, v.y, v.z, v.w, ph, pl);
        unsigned byte = ((unsigned)(r*CIN + ci))*2u ^ ((unsigned)((r & 7) << 4));
        *(uint2*)((char*)hsh + byte) = ph;
        *(uint2*)((char*)hsl + byte) = pl;
    }
    __syncthreads();

    f32x4 acc[4][4];
    const f32x4 z = {0.f, 0.f, 0.f, 0.f};
#pragma unroll
    for (int m = 0; m < 4; ++m)
#pragma unroll
        for (int n = 0; n < 4; ++n) acc[m][n] = z;

    for (int k = 0; k < 3; ++k) {
#pragma unroll
        for (int cb = 0; cb < NCHK; ++cb) {
            bf16x8 bh[4], bl[4];
#pragma unroll
            for (int n = 0; n < 4; ++n) {          // frag-order: coalesced
                size_t off = ((((size_t)k*NCHK + cb)*8 + wx*4 + n)*64 + lane)*8;
                bh[n] = *(const bf16x8*)(Wh + off);
                bl[n] = *(const bf16x8*)(Wl + off);
            }
            bf16x8 ah[4], al[4];
#pragma unroll
            for (int m = 0; m < 4; ++m) {
                int r = wy*64 + m*16 + l16 + k*DIL;
                unsigned byte = ((unsigned)(r*CIN + cb*32 + l4*8))*2u
                              ^ ((unsigned)((r & 7) << 4));
                ah[m] = *(const bf16x8*)((const char*)hsh + byte);
                al[m] = *(const bf16x8*)((const char*)hsl + byte);
            }
#pragma unroll
            for (int m = 0; m < 4; ++m)
#pragma unroll
                for (int n = 0; n < 4; ++n) {
                    acc[m][n] = __builtin_amdgcn_mfma_f32_16x16x32_bf16(ah[m], bh[n], acc[m][n], 0, 0, 0);
                    acc[m][n] = __builtin_amdgcn_mfma_f32_16x16x32_bf16(ah[m], bl[n], acc[m][n], 0, 0, 0);
                    acc[m][n] = __builtin_amdgcn_mfma_f32_16x16x32_bf16(al[m], bh[n], acc[m][n], 0, 0, 0);
                }
        }
    }

#pragma unroll
    for (int m = 0; m < 4; ++m) {
        int tl_base = wy*64 + m*16 + l4*4;
#pragma unroll
        for (int n = 0; n < 4; ++n) {
            int c = wx*64 + n*16 + l16;
            float bv = bias[c];
#pragma unroll
            for (int rg = 0; rg < 4; ++rg) {
                int tl = tl_base + rg;
                int t  = t0 + tl;
                if (t < T_) {
                    float v = acc[m][n][rg] + bv;
                    if (RES >= 1) {
                        int r = tl + DIL;
                        unsigned byte = ((unsigned)(r*CIN + c))*2u
                                      ^ ((unsigned)((r & 7) << 4));
                        float cen = bf2f(*(const ushort_t*)((const char*)hsh + byte))
                                  + bf2f(*(const ushort_t*)((const char*)hsl + byte));
                        v += (RES == 2) ? 2.0f*cen : cen;
                    }
                    Y[((size_t)b*T_ + t)*128 + c] = v;
                }
            }
        }
    }
}

// ---------------------------------------------------------------------------
// Fused ASP: v = tanh(i3 @ wa1^T + ba1); logits = v @ wa2^T + ba2 (register
// only); per-(b,chunk,c): chunk max m_ch, sum-exp, and weighted stats
// (am = sum e^(a-m_ch) x, aq = sum e^(a-m_ch) x^2) — logits never hit HBM.
__launch_bounds__(256)
__global__ void asp_fused(const float* __restrict__ I3,
                          const ushort_t* __restrict__ Wa1h, const ushort_t* __restrict__ Wa1l,
                          const ushort_t* __restrict__ Wa2h, const ushort_t* __restrict__ Wa2l,
                          const float* __restrict__ ba1, const float* __restrict__ ba2,
                          float* __restrict__ pm, float* __restrict__ ps,
                          float* __restrict__ pcm, float* __restrict__ pcq) {
    __shared__ __align__(16) char smem[65536];     // aliased regions
    ushort_t* ah_ = (ushort_t*)smem;               // [128*64] stage-1 A hi
    ushort_t* al_ = (ushort_t*)(smem + 16384);     // lo
    ushort_t* vh_ = (ushort_t*)(smem + 32768);     // v hi
    ushort_t* vl_ = (ushort_t*)(smem + 49152);     // v lo
    float*    xs_ = (float*)smem;                  // [128][128] fp32 i3 (after stage 2)
    __shared__ float redM[2][128];
    __shared__ float redS[2][128];
    __shared__ float redAM[2][128];
    __shared__ float redAQ[2][128];

    const int tid  = threadIdx.x;
    const int lane = tid & 63;
    const int wid  = tid >> 6;
    const int wy   = wid >> 1, wx = wid & 1;
    const int l16  = lane & 15, l4 = lane >> 4;
    const int ch   = blockIdx.x;
    const int b    = blockIdx.y;
    const int t0   = ch * CHL;

    // ---- stage 1: v = tanh(i3 @ wa1^T + ba1), K=128 in 2 chunks ----
    f32x4 acc1[4][2];
    const f32x4 z = {0.f,0.f,0.f,0.f};
#pragma unroll
    for (int m = 0; m < 4; ++m) { acc1[m][0] = z; acc1[m][1] = z; }

    for (int k0 = 0; k0 < 128; k0 += 64) {
        __syncthreads();
        for (int q = tid; q < 2048; q += 256) {
            int r = q >> 4, qq = (q & 15) << 2;
            int t = t0 + r;
            float4 v = make_float4(0.f,0.f,0.f,0.f);
            if (t < T_) v = *(const float4*)&I3[((size_t)b*T_ + t)*128 + k0 + qq];
            uint2 ph, pl;
            split_pack(v.x, v.y, v.z, v.w, ph, pl);
            unsigned byte = ((unsigned)(r*64 + qq))*2u ^ ((unsigned)((r & 7) << 4));
            *(uint2*)((char*)ah_ + byte) = ph;
            *(uint2*)((char*)al_ + byte) = pl;
        }
        __syncthreads();
#pragma unroll
        for (int kk = 0; kk < 64; kk += 32) {
            bf16x8 bh[2], bl[2];
#pragma unroll
            for (int n = 0; n < 2; ++n) {          // frag-order: coalesced
                size_t off = (((size_t)((k0 + kk) >> 5)*4 + wx*2 + n)*64 + lane)*8;
                bh[n] = *(const bf16x8*)(Wa1h + off);
                bl[n] = *(const bf16x8*)(Wa1l + off);
            }
            bf16x8 fh[4], fl[4];
#pragma unroll
            for (int m = 0; m < 4; ++m) {
                int r = wy*64 + m*16 + l16;
                unsigned byte = ((unsigned)(r*64 + kk + l4*8))*2u ^ ((unsigned)((r & 7) << 4));
                fh[m] = *(const bf16x8*)((const char*)ah_ + byte);
                fl[m] = *(const bf16x8*)((const char*)al_ + byte);
            }
#pragma unroll
            for (int m = 0; m < 4; ++m)
#pragma unroll
                for (int n = 0; n < 2; ++n) {
                    acc1[m][n] = __builtin_amdgcn_mfma_f32_16x16x32_bf16(fh[m], bh[n], acc1[m][n], 0, 0, 0);
                    acc1[m][n] = __builtin_amdgcn_mfma_f32_16x16x32_bf16(fh[m], bl[n], acc1[m][n], 0, 0, 0);
                    acc1[m][n] = __builtin_amdgcn_mfma_f32_16x16x32_bf16(fl[m], bh[n], acc1[m][n], 0, 0, 0);
                }
        }
    }
    // epilogue 1: tanh, write v (t x 64) to LDS bf16 hi/lo
#pragma unroll
    for (int m = 0; m < 4; ++m)
#pragma unroll
        for (int n = 0; n < 2; ++n) {
            int c = wx*32 + n*16 + l16;
            float bv = ba1[c];
            int rb = wy*64 + m*16 + l4*4;
#pragma unroll
            for (int rg = 0; rg < 4; ++rg) {
                float v = tanhf(acc1[m][n][rg] + bv);
                int r = rb + rg;
                unsigned byte = ((unsigned)(r*64 + c))*2u ^ ((unsigned)((r & 7) << 4));
                ushort_t h = f2bf(v);
                *(ushort_t*)((char*)vh_ + byte) = h;
                *(ushort_t*)((char*)vl_ + byte) = f2bf(v - bf2f(h));
            }
        }
    __syncthreads();

    // ---- stage 2: D[n][t] = sum_k wa2[n][k] v[t][k] + ba2[n] ----
    f32x4 acc2[4][4];
#pragma unroll
    for (int m = 0; m < 4; ++m)
#pragma unroll
        for (int j = 0; j < 4; ++j) acc2[m][j] = z;

#pragma unroll
    for (int kk = 0; kk < 64; kk += 32) {
        bf16x8 awh[4], awl[4];
#pragma unroll
        for (int m = 0; m < 4; ++m) {              // frag-order A: coalesced
            size_t off = (((size_t)(kk >> 5)*8 + wy*4 + m)*64 + lane)*8;
            awh[m] = *(const bf16x8*)(Wa2h + off);
            awl[m] = *(const bf16x8*)(Wa2l + off);
        }
        bf16x8 bvh[4], bvl[4];
#pragma unroll
        for (int j = 0; j < 4; ++j) {
            int r = wx*64 + j*16 + l16;
            unsigned byte = ((unsigned)(r*64 + kk + l4*8))*2u ^ ((unsigned)((r & 7) << 4));
            bvh[j] = *(const bf16x8*)((const char*)vh_ + byte);
            bvl[j] = *(const bf16x8*)((const char*)vl_ + byte);
        }
#pragma unroll
        for (int m = 0; m < 4; ++m)
#pragma unroll
            for (int j = 0; j < 4; ++j) {
                acc2[m][j] = __builtin_amdgcn_mfma_f32_16x16x32_bf16(awh[m], bvh[j], acc2[m][j], 0, 0, 0);
                acc2[m][j] = __builtin_amdgcn_mfma_f32_16x16x32_bf16(awh[m], bvl[j], acc2[m][j], 0, 0, 0);
                acc2[m][j] = __builtin_amdgcn_mfma_f32_16x16x32_bf16(awl[m], bvh[j], acc2[m][j], 0, 0, 0);
            }
    }

    // epilogue 2: bias add; per-half chunk max; restage i3 fp32; weighted sums
#pragma unroll
    for (int m = 0; m < 4; ++m) {
        const float4 bv = *(const float4*)&ba2[wy*64 + m*16 + l4*4];
#pragma unroll
        for (int j = 0; j < 4; ++j) {
            acc2[m][j][0] += bv.x; acc2[m][j][1] += bv.y;
            acc2[m][j][2] += bv.z; acc2[m][j][3] += bv.w;
        }
    }
#pragma unroll
    for (int m = 0; m < 4; ++m)
#pragma unroll
        for (int rg = 0; rg < 4; ++rg) {
            int n = wy*64 + m*16 + l4*4 + rg;
            float mx = -INFINITY;
#pragma unroll
            for (int j = 0; j < 4; ++j) {
                int tg = t0 + wx*64 + j*16 + l16;
                if (tg < T_) mx = fmaxf(mx, acc2[m][j][rg]);
            }
            mx = fmaxf(mx, __shfl_xor(mx, 1));
            mx = fmaxf(mx, __shfl_xor(mx, 2));
            mx = fmaxf(mx, __shfl_xor(mx, 4));
            mx = fmaxf(mx, __shfl_xor(mx, 8));
            if (l16 == 0) redM[wx][n] = mx;
        }
    __syncthreads();                               // stage-2 smem reads done
    // restage i3 tile as fp32 into xs_ (bank-swizzled on 4-float groups)
    for (int q = tid; q < 128*32; q += 256) {
        int r = q >> 5, c4 = (q & 31) << 2;
        int t = t0 + r;
        float4 v = make_float4(0.f,0.f,0.f,0.f);
        if (t < T_) v = *(const float4*)&I3[((size_t)b*T_ + t)*128 + c4];
        *(float4*)&xs_[r*128 + (c4 ^ ((r & 7) << 2))] = v;
    }
    __syncthreads();
#pragma unroll
    for (int m = 0; m < 4; ++m)
#pragma unroll
        for (int rg = 0; rg < 4; ++rg) {
            int n = wy*64 + m*16 + l4*4 + rg;
            const float mch = fmaxf(redM[0][n], redM[1][n]);
            float se = 0.0f, am = 0.0f, aq = 0.0f;
#pragma unroll
            for (int j = 0; j < 4; ++j) {
                int tl = wx*64 + j*16 + l16;
                int tg = t0 + tl;
                if (tg < T_) {
                    float p = expf(acc2[m][j][rg] - mch);
                    float x = xs_[tl*128 + (n ^ ((tl & 7) << 2))];
                    se += p; am += p*x; aq += p*x*x;
                }
            }
#pragma unroll
            for (int d = 1; d <= 8; d <<= 1) {
                se += __shfl_xor(se, d);
                am += __shfl_xor(am, d);
                aq += __shfl_xor(aq, d);
            }
            if (l16 == 0) { redS[wx][n] = se; redAM[wx][n] = am; redAQ[wx][n] = aq; }
        }
    __syncthreads();
    if (tid < 128) {
        float m0 = redM[0][tid], m1 = redM[1][tid];
        float M  = fmaxf(m0, m1);
        size_t o = ((size_t)b*NCH + ch)*128 + tid;
        pm[o]  = M;
        ps[o]  = redS[0][tid]  + redS[1][tid];
        pcm[o] = redAM[0][tid] + redAM[1][tid];
        pcq[o] = redAQ[0][tid] + redAQ[1][tid];
    }
}

// ---------------------------------------------------------------------------
__global__ void sm_pass_b(const float* __restrict__ pm, const float* __restrict__ ps,
                          float* __restrict__ Ms, float* __restrict__ Ss) {
    const int c = threadIdx.x, b = blockIdx.x;
    float M = -INFINITY;
    for (int ch = 0; ch < NCH; ++ch) M = fmaxf(M, pm[((size_t)b*NCH + ch)*128 + c]);
    float S = 0.0f;
    for (int ch = 0; ch < NCH; ++ch) {
        float m = pm[((size_t)b*NCH + ch)*128 + c];
        if (m > -INFINITY) S += ps[((size_t)b*NCH + ch)*128 + c] * expf(m - M);
    }
    Ms[b*128 + c] = M;
    Ss[b*128 + c] = S;
}

// stats (rescaling chunk-local partials) -> layernorm(256) -> linear 256->512
__global__ void final_kernel(const float* __restrict__ pcm, const float* __restrict__ pcq,
                             const float* __restrict__ pm,
                             const float* __restrict__ Ms, const float* __restrict__ Ss,
                             const float* __restrict__ gamma, const float* __restrict__ beta,
                             const float* __restrict__ w2, const float* __restrict__ b2,
                             float* __restrict__ out) {
    __shared__ float row[256];
    __shared__ float nrm[256];
    __shared__ float red[8];
    const int tid = threadIdx.x, b = blockIdx.x;
    if (tid < 128) {
        const float M = Ms[b*128 + tid];
        float sm = 0.0f, sq = 0.0f;
        for (int ch = 0; ch < NCH; ++ch) {
            size_t o = ((size_t)b*NCH + ch)*128 + tid;
            float m = pm[o];
            if (m > -INFINITY) {
                float e = expf(m - M);
                sm += pcm[o]*e;
                sq += pcq[o]*e;
            }
        }
        float S = Ss[b*128 + tid];
        float mean = sm / S;
        float q    = sq / S;
        float resid = q - mean*mean;
        float stdv  = sqrtf(fmaxf(resid, 1e-9f));
        row[tid]       = mean;
        row[128 + tid] = stdv;
    }
    __syncthreads();
    float v  = row[tid];
    float s1 = v, s2 = v*v;
    for (int off = 32; off >= 1; off >>= 1) {
        s1 += __shfl_down(s1, off, 64);
        s2 += __shfl_down(s2, off, 64);
    }
    if ((tid & 63) == 0) { red[tid >> 6] = s1; red[4 + (tid >> 6)] = s2; }
    __syncthreads();
    float S1 = red[0] + red[1] + red[2] + red[3];
    float S2 = red[4] + red[5] + red[6] + red[7];
    float mu  = S1 / 256.0f;
    float var = S2 / 256.0f - mu*mu;
    float inv = 1.0f / sqrtf(var + 1e-5f);
    nrm[tid] = (v - mu)*inv*gamma[tid] + beta[tid];
    __syncthreads();
#pragma unroll
    for (int oo = 0; oo < 2; ++oo) {
        int o = tid + oo*256;
        float acc = b2[o];
        const float4* wr = (const float4*)&w2[(size_t)o*256];
        for (int j = 0; j < 64; ++j) {
            float4 w = wr[j];
            acc += w.x*nrm[j*4] + w.y*nrm[j*4+1] + w.z*nrm[j*4+2] + w.w*nrm[j*4+3];
        }
        out[(size_t)b*512 + o] = acc;
    }
}

// ---------------------------------------------------------------------------
extern "C" void kernel_launch(void* const* d_in, const int* in_sizes, int n_in,
                              void* d_out, int out_size, void* d_ws, size_t ws_size,
                              hipStream_t stream) {
    const float* x      = (const float*)d_in[0];
    const float* bp     = (const float*)d_in[1];
    const float* w_lin1 = (const float*)d_in[2];
    const float* b_lin1 = (const float*)d_in[3];
    const float* wc1    = (const float*)d_in[4];
    const float* bc1    = (const float*)d_in[5];
    const float* wc2    = (const float*)d_in[6];
    const float* bc2    = (const float*)d_in[7];
    const float* wc3    = (const float*)d_in[8];
    const float* bc3    = (const float*)d_in[9];
    const float* wa1    = (const float*)d_in[10];
    const float* ba1    = (const float*)d_in[11];
    const float* wa2    = (const float*)d_in[12];
    const float* ba2    = (const float*)d_in[13];
    const float* gamma  = (const float*)d_in[14];
    const float* beta   = (const float*)d_in[15];
    const float* wl2    = (const float*)d_in[16];
    const float* bl2    = (const float*)d_in[17];

    float* ws   = (float*)d_ws;
    float* bs   = ws + OFF_BS;
    ushort_t* weh  = (ushort_t*)(ws + OFF_WEFF);
    ushort_t* wel  = weh + 64*320;
    float* wtail   = ws + OFF_WTAIL;
    ushort_t* w1h  = (ushort_t*)(ws + OFF_W1);
    ushort_t* w1l  = w1h + 3*128*64;
    ushort_t* w2h  = (ushort_t*)(ws + OFF_W2);
    ushort_t* w2l  = w2h + 3*128*128;
    ushort_t* w3h  = (ushort_t*)(ws + OFF_W3);
    ushort_t* w3l  = w3h + 3*128*128;
    ushort_t* wa1h = (ushort_t*)(ws + OFF_WA1);
    ushort_t* wa1l = wa1h + 64*128;
    ushort_t* wa2h = (ushort_t*)(ws + OFF_WA2);
    ushort_t* wa2l = wa2h + 128*64;
    float* pm   = ws + OFF_PM;
    float* ps   = ws + OFF_PS;
    float* Ms   = ws + OFF_MS;
    float* Ss   = ws + OFF_SS;
    float* pcm  = ws + OFF_PCM;
    float* pcq  = ws + OFF_PCQ;
    float* h    = ws + OFF_H;
    float* bufA = ws + OFF_A;    // i1, then i3

    sort_kernel<<<dim3(1), dim3(64), 0, stream>>>(bp, bs);
    prep_kernel<<<dim3(624), dim3(256), 0, stream>>>(bs, w_lin1, wc1, wc2, wc3, wa1, wa2,
                                                     weh, wel, wtail, w1h, w1l, w2h, w2l,
                                                     w3h, w3l, wa1h, wa1l, wa2h, wa2l);
    // h = relu(x @ Weff^T + b_lin1)
    lin1_mfma<<<dim3(R_/128), dim3(256), 0, stream>>>(x, weh, wel, wtail, b_lin1, h);
    // i1 = conv1(h) + b  (bufB used as s-buffer below; reuse OFF_BB region)
    float* bufB = ws + OFF_BB;
    dconv_mfma<64, 2, 0><<<dim3(24, B_), dim3(256), 0, stream>>>(h, w1h, w1l, bc1, bufA);
    // s = i1 + i2 = conv2(i1) + b + 2*i1
    dconv_mfma<128, 3, 2><<<dim3(24, B_), dim3(256), 0, stream>>>(bufA, w2h, w2l, bc2, bufB);
    // i3 = conv3(s) + b + s
    dconv_mfma<128, 4, 1><<<dim3(24, B_), dim3(256), 0, stream>>>(bufB, w3h, w3l, bc3, bufA);
    // fused asp1+asp2+softmax partials+weighted stats (no logits to HBM)
    asp_fused<<<dim3(NCH, B_), dim3(256), 0, stream>>>(bufA, wa1h, wa1l, wa2h, wa2l,
                                                       ba1, ba2, pm, ps, pcm, pcq);
    sm_pass_b<<<dim3(B_), dim3(128), 0, stream>>>(pm, ps, Ms, Ss);
    final_kernel<<<dim3(B_), dim3(256), 0, stream>>>(pcm, pcq, pm, Ms, Ss, gamma, beta,
                                                     wl2, bl2, (float*)d_out);
}

// Round 9
// 484.141 us; speedup vs baseline: 1.2002x; 1.2002x over previous
//
#include <hip/hip_runtime.h>
#include <math.h>

// ---------------------------------------------------------------------------
// ResCNN_ASP_SpeakerEncoder — v8: dconv back to TT=64 (4 blocks/CU) with
// software-pipelined weight-chunk register prefetch (frag-order coalesced
// loads). ASP fusion (no logits to HBM) kept from v7.
// ---------------------------------------------------------------------------

constexpr int B_  = 64;
constexpr int T_  = 3000;
constexpr int NB_ = 257;   // NBINS
constexpr int R_  = B_ * T_;           // 192000 rows
constexpr int NCH = 24;                // softmax T-chunks (24 x 128)
constexpr int CHL = 128;

// workspace layout (float offsets)
constexpr size_t OFF_BS    = 0;                            // sorted binpoints (82)
constexpr size_t OFF_WEFF  = 128;                          // ushort hi[64*256]+lo (frag order)
constexpr size_t OFF_WTAIL = OFF_WEFF + 20480;             // fp32 [64]
constexpr size_t OFF_W1    = OFF_WTAIL + 128;              // ushort hi[3*128*64]+lo
constexpr size_t OFF_W2    = OFF_W1  + 3*64*128;           // ushort hi[3*128*128]+lo
constexpr size_t OFF_W3    = OFF_W2  + 3*128*128;
constexpr size_t OFF_WA1   = OFF_W3  + 3*128*128;          // ushort hi[64*128]+lo
constexpr size_t OFF_WA2   = OFF_WA1 + 8192;               // ushort hi[128*64]+lo
constexpr size_t SZ_P      = (size_t)B_*NCH*128;
constexpr size_t OFF_PM    = OFF_WA2 + 8192;
constexpr size_t OFF_PS    = OFF_PM  + SZ_P;
constexpr size_t OFF_MS    = OFF_PS  + SZ_P;               // [B][128]
constexpr size_t OFF_SS    = OFF_MS  + (size_t)B_*128;
constexpr size_t OFF_PCM   = OFF_SS  + (size_t)B_*128;
constexpr size_t OFF_PCQ   = OFF_PCM + SZ_P;
constexpr size_t OFF_H     = OFF_PCQ + SZ_P;               // [R][64]  (h)
constexpr size_t OFF_A     = OFF_H   + (size_t)R_*64;      // [R][128] (i1, later i3)
constexpr size_t OFF_BB    = OFF_A   + (size_t)R_*128;     // [R][128] (s)

typedef __attribute__((ext_vector_type(8))) short  bf16x8;
typedef __attribute__((ext_vector_type(4))) float  f32x4;
typedef __attribute__((ext_vector_type(4), aligned(4))) float float4a;  // 4B-aligned ok
typedef unsigned short ushort_t;

__device__ inline ushort_t f2bf(float f) {                // RNE f32->bf16
    unsigned u = __float_as_uint(f);
    unsigned r = u + 0x7FFFu + ((u >> 16) & 1u);
    return (ushort_t)(r >> 16);
}
__device__ inline float bf2f(ushort_t h) {
    return __uint_as_float(((unsigned)h) << 16);
}

// hw-packed split: v -> bf16 hi pair + bf16 lo pair (RNE), 6 insts per 4 elems
__device__ inline void split_pack(float x, float y, float z, float w,
                                  uint2 &ph, uint2 &pl) {
    unsigned hx, hy;
    asm("v_cvt_pk_bf16_f32 %0, %1, %2" : "=v"(hx) : "v"(x), "v"(y));
    asm("v_cvt_pk_bf16_f32 %0, %1, %2" : "=v"(hy) : "v"(z), "v"(w));
    float l0 = x - __uint_as_float(hx << 16);
    float l1 = y - __uint_as_float(hx & 0xFFFF0000u);
    float l2 = z - __uint_as_float(hy << 16);
    float l3 = w - __uint_as_float(hy & 0xFFFF0000u);
    unsigned lx, ly;
    asm("v_cvt_pk_bf16_f32 %0, %1, %2" : "=v"(lx) : "v"(l0), "v"(l1));
    asm("v_cvt_pk_bf16_f32 %0, %1, %2" : "=v"(ly) : "v"(l2), "v"(l3));
    ph.x = hx; ph.y = hy; pl.x = lx; pl.y = ly;
}

// ---------------------------------------------------------------------------
__global__ void sort_kernel(const float* __restrict__ bp, float* __restrict__ bs) {
    if (threadIdx.x == 0) {
        float tmp[82];
        for (int i = 0; i < 82; ++i) tmp[i] = bp[i];
        for (int i = 1; i < 82; ++i) {
            float key = tmp[i];
            int j = i - 1;
            while (j >= 0 && tmp[j] > key) { tmp[j+1] = tmp[j]; --j; }
            tmp[j+1] = key;
        }
        for (int i = 0; i < 82; ++i) bs[i] = tmp[i];
    }
}

// Fragment-order packing (B: lane&15=col, lane>>4=k-octet; A: lane&15=row).
__global__ void prep_kernel(const float* __restrict__ bs, const float* __restrict__ wl1,
                            const float* __restrict__ wc1, const float* __restrict__ wc2,
                            const float* __restrict__ wc3, const float* __restrict__ wa1,
                            const float* __restrict__ wa2,
                            ushort_t* __restrict__ weh, ushort_t* __restrict__ wel,
                            float* __restrict__ wtail,
                            ushort_t* __restrict__ w1h, ushort_t* __restrict__ w1l,
                            ushort_t* __restrict__ w2h, ushort_t* __restrict__ w2l,
                            ushort_t* __restrict__ w3h, ushort_t* __restrict__ w3l,
                            ushort_t* __restrict__ wa1h, ushort_t* __restrict__ wa1l,
                            ushort_t* __restrict__ wa2h, ushort_t* __restrict__ wa2l) {
    int gid = blockIdx.x * 256 + threadIdx.x;
    if (gid < 64*320) {                            // Weff[o][f]
        int o = gid / 320, f = gid % 320;
        if (f > 256) return;
        float acc = 0.0f;
        if (f == 0) acc = wl1[o*80];               // filt[:,:,0] = x[:,:,0]
        else {
            for (int n = 1; n < 79; ++n) {         // fb rows 1..78 (row 79 zero)
                float bn = bs[n], bn1 = bs[n+1], bn2 = bs[n+2];
                int ibn  = (int)floorf(bn);
                int ibn1 = (int)floorf(bn1);
                int ibn2 = (int)floorf(bn2);
                float fbv = 0.0f;
                if (f >= ibn && f < ibn1) {
                    float d = (bn1-bn)*(bn1-bn);
                    fbv = ((float)f - bn) / (d > 0.0f ? d : 1.0f);
                } else if (f >= ibn1 && f < ibn2) {
                    float d = (bn2-bn1)*(bn2-bn1);
                    fbv = (bn2 - (float)f) / (d > 0.0f ? d : 1.0f);
                }
                acc += wl1[o*80 + n] * fbv;
            }
        }
        if (f == 256) { wtail[o] = acc; return; }  // fp32 rank-1 tail column
        int kc = f >> 5, lane = ((f & 31) >> 3)*16 + (o & 15), e = f & 7;
        size_t dst = (((size_t)kc*4 + (o >> 4))*64 + lane)*8 + e;
        ushort_t h = f2bf(acc);
        weh[dst] = h; wel[dst] = f2bf(acc - bf2f(h));
        return;
    }
    gid -= 64*320;
    if (gid < 3*128*64) {                          // conv1: [k][c][ci=64]
        int k = gid / (128*64), rem = gid % (128*64);
        int c = rem >> 6, ci = rem & 63;
        float v = wc1[(c*64 + ci)*3 + k];
        int lane = ((ci & 31) >> 3)*16 + (c & 15), e = ci & 7;
        size_t dst = ((((size_t)k*2 + (ci >> 5))*8 + (c >> 4))*64 + lane)*8 + e;
        ushort_t h = f2bf(v);
        w1h[dst] = h; w1l[dst] = f2bf(v - bf2f(h));
        return;
    }
    gid -= 3*128*64;
    if (gid < 3*128*128) {                         // conv2: [k][c][ci=128]
        int k = gid / (128*128), rem = gid % (128*128);
        int c = rem >> 7, ci = rem & 127;
        float v = wc2[(c*128 + ci)*3 + k];
        int lane = ((ci & 31) >> 3)*16 + (c & 15), e = ci & 7;
        size_t dst = ((((size_t)k*4 + (ci >> 5))*8 + (c >> 4))*64 + lane)*8 + e;
        ushort_t h = f2bf(v);
        w2h[dst] = h; w2l[dst] = f2bf(v - bf2f(h));
        return;
    }
    gid -= 3*128*128;
    if (gid < 3*128*128) {                         // conv3
        int k = gid / (128*128), rem = gid % (128*128);
        int c = rem >> 7, ci = rem & 127;
        float v = wc3[(c*128 + ci)*3 + k];
        int lane = ((ci & 31) >> 3)*16 + (c & 15), e = ci & 7;
        size_t dst = ((((size_t)k*4 + (ci >> 5))*8 + (c >> 4))*64 + lane)*8 + e;
        ushort_t h = f2bf(v);
        w3h[dst] = h; w3l[dst] = f2bf(v - bf2f(h));
        return;
    }
    gid -= 3*128*128;
    if (gid < 64*128) {                            // wa1 [c=64][ci=128]
        int c = gid >> 7, ci = gid & 127;
        float v = wa1[gid];
        int lane = ((ci & 31) >> 3)*16 + (c & 15), e = ci & 7;
        size_t dst = (((size_t)(ci >> 5)*4 + (c >> 4))*64 + lane)*8 + e;
        ushort_t h = f2bf(v);
        wa1h[dst] = h; wa1l[dst] = f2bf(v - bf2f(h));
        return;
    }
    gid -= 64*128;
    if (gid < 128*64) {                            // wa2 [n=128][ci=64] (A operand)
        int n = gid >> 6, ci = gid & 63;
        float v = wa2[gid];
        int lane = ((ci & 31) >> 3)*16 + (n & 15), e = ci & 7;
        size_t dst = (((size_t)(ci >> 5)*8 + (n >> 4))*64 + lane)*8 + e;
        ushort_t h = f2bf(v);
        wa2h[dst] = h; wa2l[dst] = f2bf(v - bf2f(h));
        return;
    }
}

// ---------------------------------------------------------------------------
// lin1: h[t][c] = relu( x[t][:257] . Weff[c][:] + b[c] ).
__launch_bounds__(256)
__global__ void lin1_mfma(const float* __restrict__ X,
                          const ushort_t* __restrict__ Wh, const ushort_t* __restrict__ Wl,
                          const float* __restrict__ wtail,
                          const float* __restrict__ bias, float* __restrict__ H) {
    __shared__ __align__(16) ushort_t ash[128*64];
    __shared__ __align__(16) ushort_t asl[128*64];
    __shared__ float xs[128];
    __shared__ float wts[64];
    const int tid  = threadIdx.x;
    const int lane = tid & 63;
    const int wid  = tid >> 6;
    const int wy   = wid >> 1, wx = wid & 1;
    const int l16  = lane & 15, l4 = lane >> 4;
    const int r0   = blockIdx.x * 128;

    if (tid < 128)       xs[tid] = X[(size_t)(r0 + tid)*NB_ + 256];
    else if (tid < 192)  wts[tid - 128] = wtail[tid - 128];

#define LIN1_LOAD(dst, k0)                                            \
    _Pragma("unroll")                                                 \
    for (int i = 0; i < 8; ++i) {                                     \
        int q = tid + i*256; int r = q >> 4, cc = (q & 15) << 2;      \
        dst[i] = *(const float4a*)(X + (size_t)(r0 + r)*NB_ + (k0) + cc); \
    }
#define LIN1_CW(src)                                                  \
    _Pragma("unroll")                                                 \
    for (int i = 0; i < 8; ++i) {                                     \
        int q = tid + i*256; int r = q >> 4, cc = (q & 15) << 2;      \
        uint2 ph, pl;                                                 \
        split_pack(src[i].x, src[i].y, src[i].z, src[i].w, ph, pl);   \
        unsigned byte = ((unsigned)(r*64 + cc))*2u ^ ((unsigned)((r & 7) << 4)); \
        *(uint2*)((char*)ash + byte) = ph;                            \
        *(uint2*)((char*)asl + byte) = pl;                            \
    }

    float4a bufA[8], bufB[8];
    LIN1_LOAD(bufA, 0);

    f32x4 acc[4][2];
    const f32x4 z = {0.f,0.f,0.f,0.f};
#pragma unroll
    for (int m = 0; m < 4; ++m) { acc[m][0] = z; acc[m][1] = z; }

#pragma unroll
    for (int ck = 0; ck < 4; ++ck) {
        const float4a* cur = (ck & 1) ? bufB : bufA;
        float4a*       nxt = (ck & 1) ? bufA : bufB;
        if (ck < 3) LIN1_LOAD(nxt, (ck + 1)*64);
        LIN1_CW(cur);
        __syncthreads();
#pragma unroll
        for (int kk = 0; kk < 64; kk += 32) {
            bf16x8 bh[2], bl[2];
#pragma unroll
            for (int n = 0; n < 2; ++n) {          // frag-order: coalesced
                size_t off = (((size_t)(ck*2 + (kk >> 5))*4 + wx*2 + n)*64 + lane)*8;
                bh[n] = *(const bf16x8*)(Wh + off);
                bl[n] = *(const bf16x8*)(Wl + off);
            }
            bf16x8 fh[4], fl[4];
#pragma unroll
            for (int m = 0; m < 4; ++m) {
                int r = wy*64 + m*16 + l16;
                unsigned byte = ((unsigned)(r*64 + kk + l4*8))*2u ^ ((unsigned)((r & 7) << 4));
                fh[m] = *(const bf16x8*)((const char*)ash + byte);
                fl[m] = *(const bf16x8*)((const char*)asl + byte);
            }
#pragma unroll
            for (int m = 0; m < 4; ++m)
#pragma unroll
                for (int n = 0; n < 2; ++n) {
                    acc[m][n] = __builtin_amdgcn_mfma_f32_16x16x32_bf16(fh[m], bh[n], acc[m][n], 0, 0, 0);
                    acc[m][n] = __builtin_amdgcn_mfma_f32_16x16x32_bf16(fh[m], bl[n], acc[m][n], 0, 0, 0);
                    acc[m][n] = __builtin_amdgcn_mfma_f32_16x16x32_bf16(fl[m], bh[n], acc[m][n], 0, 0, 0);
                }
        }
        __syncthreads();
    }
#undef LIN1_LOAD
#undef LIN1_CW

#pragma unroll
    for (int m = 0; m < 4; ++m)
#pragma unroll
        for (int n = 0; n < 2; ++n) {
            int c = wx*32 + n*16 + l16;
            float bv = bias[c];
            float wc = wts[c];
            int rbl = wy*64 + m*16 + l4*4;
#pragma unroll
            for (int rg = 0; rg < 4; ++rg) {
                int rl = rbl + rg;
                float v = acc[m][n][rg] + bv + xs[rl]*wc;   // fp32 k=256 tail
                H[(size_t)(r0 + rl)*64 + c] = fmaxf(v, 0.0f);
            }
        }
}

// ---------------------------------------------------------------------------
// Dilated conv (K=3) via split-bf16 MFMA. TT=64 (LDS 36KB -> 4 blocks/CU),
// frag-order weights, software-pipelined register prefetch of next chunk.
template<int CIN, int DIL, int RES>
__launch_bounds__(256, 3)
__global__ void dconv_mfma(const float* __restrict__ X,
                           const ushort_t* __restrict__ Wh,
                           const ushort_t* __restrict__ Wl,
                           const float* __restrict__ bias, float* __restrict__ Y) {
    constexpr int TT   = 64;
    constexpr int HS   = TT + 2*DIL;
    constexpr int NCHK = CIN/32;
    constexpr int NC   = 3*NCHK;           // flattened (k, cb) chunks
    __shared__ __align__(16) ushort_t hsh[HS*CIN];
    __shared__ __align__(16) ushort_t hsl[HS*CIN];

    const int tid  = threadIdx.x;
    const int lane = tid & 63;
    const int wid  = tid >> 6;
    const int wy   = wid >> 1;            // rows wy*32 + m*16
    const int wx   = wid & 1;             // cols wx*64 + n*16
    const int l16  = lane & 15;
    const int l4   = lane >> 4;
    const int t0   = blockIdx.x * TT;
    const int b    = blockIdx.y;

    for (int idx = tid; idx < HS*CIN/4; idx += 256) {
        int e  = idx << 2;
        int r  = e / CIN, ci = e % CIN;
        int t  = t0 - DIL + r;
        float4 v = make_float4(0.f, 0.f, 0.f, 0.f);
        if (t >= 0 && t < T_) v = *(const float4*)&X[((size_t)b*T_ + t)*CIN + ci];
        uint2 ph, pl;
        split_pack(v.x, v.y, v.z, v.w, ph, pl);
        unsigned byte = ((unsigned)(r*CIN + ci))*2u ^ ((unsigned)((r & 7) << 4));
        *(uint2*)((char*)hsh + byte) = ph;
        *(uint2*)((char*)hsl + byte) = pl;
    }

    f32x4 acc[2][4];
    const f32x4 z = {0.f, 0.f, 0.f, 0.f};
#pragma unroll
    for (int m = 0; m < 2; ++m)
#pragma unroll
        for (int n = 0; n < 4; ++n) acc[m][n] = z;

    // weight prefetch pipeline (double-buffered register sets)
    bf16x8 wh0[4], wl0[4], wh1[4], wl1[4];
#define DCONV_LOADW(q, WH, WL)                                               \
    _Pragma("unroll")                                                        \
    for (int n = 0; n < 4; ++n) {                                            \
        size_t off = ((((size_t)(q))*8 + wx*4 + n)*64 + lane)*8;             \
        WH[n] = *(const bf16x8*)(Wh + off);                                  \
        WL[n] = *(const bf16x8*)(Wl + off);                                  \
    }

    DCONV_LOADW(0, wh0, wl0);
    __syncthreads();                       // staging visible

#pragma unroll
    for (int q = 0; q < NC; ++q) {
        const bf16x8* ch_ = (q & 1) ? wh1 : wh0;
        const bf16x8* cl_ = (q & 1) ? wl1 : wl0;
        bf16x8* nh_ = (q & 1) ? wh0 : wh1;
        bf16x8* nl_ = (q & 1) ? wl0 : wl1;
        if (q + 1 < NC) { DCONV_LOADW(q + 1, nh_, nl_); }
        const int k  = q / NCHK;
        const int cb = q % NCHK;
        bf16x8 ah[2], al[2];
#pragma unroll
        for (int m = 0; m < 2; ++m) {
            int r = wy*32 + m*16 + l16 + k*DIL;
            unsigned byte = ((unsigned)(r*CIN + cb*32 + l4*8))*2u
                          ^ ((unsigned)((r & 7) << 4));
            ah[m] = *(const bf16x8*)((const char*)hsh + byte);
            al[m] = *(const bf16x8*)((const char*)hsl + byte);
        }
#pragma unroll
        for (int m = 0; m < 2; ++m)
#pragma unroll
            for (int n = 0; n < 4; ++n) {
                acc[m][n] = __builtin_amdgcn_mfma_f32_16x16x32_bf16(ah[m], ch_[n], acc[m][n], 0, 0, 0);
                acc[m][n] = __builtin_amdgcn_mfma_f32_16x16x32_bf16(ah[m], cl_[n], acc[m][n], 0, 0, 0);
                acc[m][n] = __builtin_amdgcn_mfma_f32_16x16x32_bf16(al[m], ch_[n], acc[m][n], 0, 0, 0);
            }
    }
#undef DCONV_LOADW

#pragma unroll
    for (int m = 0; m < 2; ++m) {
        int tl_base = wy*32 + m*16 + l4*4;
#pragma unroll
        for (int n = 0; n < 4; ++n) {
            int c = wx*64 + n*16 + l16;
            float bv = bias[c];
#pragma unroll
            for (int rg = 0; rg < 4; ++rg) {
                int tl = tl_base + rg;
                int t  = t0 + tl;
                if (t < T_) {
                    float v = acc[m][n][rg] + bv;
                    if (RES >= 1) {
                        int r = tl + DIL;
                        unsigned byte = ((unsigned)(r*CIN + c))*2u
                                      ^ ((unsigned)((r & 7) << 4));
                        float cen = bf2f(*(const ushort_t*)((const char*)hsh + byte))
                                  + bf2f(*(const ushort_t*)((const char*)hsl + byte));
                        v += (RES == 2) ? 2.0f*cen : cen;
                    }
                    Y[((size_t)b*T_ + t)*128 + c] = v;
                }
            }
        }
    }
}

// ---------------------------------------------------------------------------
// Fused ASP: v = tanh(i3 @ wa1^T + ba1); logits = v @ wa2^T + ba2 (register
// only); per-(b,chunk,c): chunk max, sum-exp, and weighted stats.
__launch_bounds__(256)
__global__ void asp_fused(const float* __restrict__ I3,
                          const ushort_t* __restrict__ Wa1h, const ushort_t* __restrict__ Wa1l,
                          const ushort_t* __restrict__ Wa2h, const ushort_t* __restrict__ Wa2l,
                          const float* __restrict__ ba1, const float* __restrict__ ba2,
                          float* __restrict__ pm, float* __restrict__ ps,
                          float* __restrict__ pcm, float* __restrict__ pcq) {
    __shared__ __align__(16) char smem[65536];     // aliased regions
    ushort_t* ah_ = (ushort_t*)smem;               // [128*64] stage-1 A hi
    ushort_t* al_ = (ushort_t*)(smem + 16384);     // lo
    ushort_t* vh_ = (ushort_t*)(smem + 32768);     // v hi
    ushort_t* vl_ = (ushort_t*)(smem + 49152);     // v lo
    float*    xs_ = (float*)smem;                  // [128][128] fp32 i3 (after stage 2)
    __shared__ float redM[2][128];
    __shared__ float redS[2][128];
    __shared__ float redAM[2][128];
    __shared__ float redAQ[2][128];

    const int tid  = threadIdx.x;
    const int lane = tid & 63;
    const int wid  = tid >> 6;
    const int wy   = wid >> 1, wx = wid & 1;
    const int l16  = lane & 15, l4 = lane >> 4;
    const int ch   = blockIdx.x;
    const int b    = blockIdx.y;
    const int t0   = ch * CHL;

    // ---- stage 1: v = tanh(i3 @ wa1^T + ba1), K=128 in 2 chunks ----
    f32x4 acc1[4][2];
    const f32x4 z = {0.f,0.f,0.f,0.f};
#pragma unroll
    for (int m = 0; m < 4; ++m) { acc1[m][0] = z; acc1[m][1] = z; }

    for (int k0 = 0; k0 < 128; k0 += 64) {
        __syncthreads();
        for (int q = tid; q < 2048; q += 256) {
            int r = q >> 4, qq = (q & 15) << 2;
            int t = t0 + r;
            float4 v = make_float4(0.f,0.f,0.f,0.f);
            if (t < T_) v = *(const float4*)&I3[((size_t)b*T_ + t)*128 + k0 + qq];
            uint2 ph, pl;
            split_pack(v.x, v.y, v.z, v.w, ph, pl);
            unsigned byte = ((unsigned)(r*64 + qq))*2u ^ ((unsigned)((r & 7) << 4));
            *(uint2*)((char*)ah_ + byte) = ph;
            *(uint2*)((char*)al_ + byte) = pl;
        }
        __syncthreads();
#pragma unroll
        for (int kk = 0; kk < 64; kk += 32) {
            bf16x8 bh[2], bl[2];
#pragma unroll
            for (int n = 0; n < 2; ++n) {          // frag-order: coalesced
                size_t off = (((size_t)((k0 + kk) >> 5)*4 + wx*2 + n)*64 + lane)*8;
                bh[n] = *(const bf16x8*)(Wa1h + off);
                bl[n] = *(const bf16x8*)(Wa1l + off);
            }
            bf16x8 fh[4], fl[4];
#pragma unroll
            for (int m = 0; m < 4; ++m) {
                int r = wy*64 + m*16 + l16;
                unsigned byte = ((unsigned)(r*64 + kk + l4*8))*2u ^ ((unsigned)((r & 7) << 4));
                fh[m] = *(const bf16x8*)((const char*)ah_ + byte);
                fl[m] = *(const bf16x8*)((const char*)al_ + byte);
            }
#pragma unroll
            for (int m = 0; m < 4; ++m)
#pragma unroll
                for (int n = 0; n < 2; ++n) {
                    acc1[m][n] = __builtin_amdgcn_mfma_f32_16x16x32_bf16(fh[m], bh[n], acc1[m][n], 0, 0, 0);
                    acc1[m][n] = __builtin_amdgcn_mfma_f32_16x16x32_bf16(fh[m], bl[n], acc1[m][n], 0, 0, 0);
                    acc1[m][n] = __builtin_amdgcn_mfma_f32_16x16x32_bf16(fl[m], bh[n], acc1[m][n], 0, 0, 0);
                }
        }
    }
    // epilogue 1: tanh, write v (t x 64) to LDS bf16 hi/lo
#pragma unroll
    for (int m = 0; m < 4; ++m)
#pragma unroll
        for (int n = 0; n < 2; ++n) {
            int c = wx*32 + n*16 + l16;
            float bv = ba1[c];
            int rb = wy*64 + m*16 + l4*4;
#pragma unroll
            for (int rg = 0; rg < 4; ++rg) {
                float v = tanhf(acc1[m][n][rg] + bv);
                int r = rb + rg;
                unsigned byte = ((unsigned)(r*64 + c))*2u ^ ((unsigned)((r & 7) << 4));
                ushort_t h = f2bf(v);
                *(ushort_t*)((char*)vh_ + byte) = h;
                *(ushort_t*)((char*)vl_ + byte) = f2bf(v - bf2f(h));
            }
        }
    __syncthreads();

    // ---- stage 2: D[n][t] = sum_k wa2[n][k] v[t][k] + ba2[n] ----
    f32x4 acc2[4][4];
#pragma unroll
    for (int m = 0; m < 4; ++m)
#pragma unroll
        for (int j = 0; j < 4; ++j) acc2[m][j] = z;

#pragma unroll
    for (int kk = 0; kk < 64; kk += 32) {
        bf16x8 awh[4], awl[4];
#pragma unroll
        for (int m = 0; m < 4; ++m) {              // frag-order A: coalesced
            size_t off = (((size_t)(kk >> 5)*8 + wy*4 + m)*64 + lane)*8;
            awh[m] = *(const bf16x8*)(Wa2h + off);
            awl[m] = *(const bf16x8*)(Wa2l + off);
        }
        bf16x8 bvh[4], bvl[4];
#pragma unroll
        for (int j = 0; j < 4; ++j) {
            int r = wx*64 + j*16 + l16;
            unsigned byte = ((unsigned)(r*64 + kk + l4*8))*2u ^ ((unsigned)((r & 7) << 4));
            bvh[j] = *(const bf16x8*)((const char*)vh_ + byte);
            bvl[j] = *(const bf16x8*)((const char*)vl_ + byte);
        }
#pragma unroll
        for (int m = 0; m < 4; ++m)
#pragma unroll
            for (int j = 0; j < 4; ++j) {
                acc2[m][j] = __builtin_amdgcn_mfma_f32_16x16x32_bf16(awh[m], bvh[j], acc2[m][j], 0, 0, 0);
                acc2[m][j] = __builtin_amdgcn_mfma_f32_16x16x32_bf16(awh[m], bvl[j], acc2[m][j], 0, 0, 0);
                acc2[m][j] = __builtin_amdgcn_mfma_f32_16x16x32_bf16(awl[m], bvh[j], acc2[m][j], 0, 0, 0);
            }
    }

    // epilogue 2: bias add; per-half chunk max; restage i3 fp32; weighted sums
#pragma unroll
    for (int m = 0; m < 4; ++m) {
        const float4 bv = *(const float4*)&ba2[wy*64 + m*16 + l4*4];
#pragma unroll
        for (int j = 0; j < 4; ++j) {
            acc2[m][j][0] += bv.x; acc2[m][j][1] += bv.y;
            acc2[m][j][2] += bv.z; acc2[m][j][3] += bv.w;
        }
    }
#pragma unroll
    for (int m = 0; m < 4; ++m)
#pragma unroll
        for (int rg = 0; rg < 4; ++rg) {
            int n = wy*64 + m*16 + l4*4 + rg;
            float mx = -INFINITY;
#pragma unroll
            for (int j = 0; j < 4; ++j) {
                int tg = t0 + wx*64 + j*16 + l16;
                if (tg < T_) mx = fmaxf(mx, acc2[m][j][rg]);
            }
            mx = fmaxf(mx, __shfl_xor(mx, 1));
            mx = fmaxf(mx, __shfl_xor(mx, 2));
            mx = fmaxf(mx, __shfl_xor(mx, 4));
            mx = fmaxf(mx, __shfl_xor(mx, 8));
            if (l16 == 0) redM[wx][n] = mx;
        }
    __syncthreads();                               // stage-2 smem reads done
    // restage i3 tile as fp32 into xs_ (bank-swizzled on 4-float groups)
    for (int q = tid; q < 128*32; q += 256) {
        int r = q >> 5, c4 = (q & 31) << 2;
        int t = t0 + r;
        float4 v = make_float4(0.f,0.f,0.f,0.f);
        if (t < T_) v = *(const float4*)&I3[((size_t)b*T_ + t)*128 + c4];
        *(float4*)&xs_[r*128 + (c4 ^ ((r & 7) << 2))] = v;
    }
    __syncthreads();
#pragma unroll
    for (int m = 0; m < 4; ++m)
#pragma unroll
        for (int rg = 0; rg < 4; ++rg) {
            int n = wy*64 + m*16 + l4*4 + rg;
            const float mch = fmaxf(redM[0][n], redM[1][n]);
            float se = 0.0f, am = 0.0f, aq = 0.0f;
#pragma unroll
            for (int j = 0; j < 4; ++j) {
                int tl = wx*64 + j*16 + l16;
                int tg = t0 + tl;
                if (tg < T_) {
                    float p = expf(acc2[m][j][rg] - mch);
                    float x = xs_[tl*128 + (n ^ ((tl & 7) << 2))];
                    se += p; am += p*x; aq += p*x*x;
                }
            }
#pragma unroll
            for (int d = 1; d <= 8; d <<= 1) {
                se += __shfl_xor(se, d);
                am += __shfl_xor(am, d);
                aq += __shfl_xor(aq, d);
            }
            if (l16 == 0) { redS[wx][n] = se; redAM[wx][n] = am; redAQ[wx][n] = aq; }
        }
    __syncthreads();
    if (tid < 128) {
        float m0 = redM[0][tid], m1 = redM[1][tid];
        float M  = fmaxf(m0, m1);
        size_t o = ((size_t)b*NCH + ch)*128 + tid;
        pm[o]  = M;
        ps[o]  = redS[0][tid]  + redS[1][tid];
        pcm[o] = redAM[0][tid] + redAM[1][tid];
        pcq[o] = redAQ[0][tid] + redAQ[1][tid];
    }
}

// ---------------------------------------------------------------------------
__global__ void sm_pass_b(const float* __restrict__ pm, const float* __restrict__ ps,
                          float* __restrict__ Ms, float* __restrict__ Ss) {
    const int c = threadIdx.x, b = blockIdx.x;
    float M = -INFINITY;
    for (int ch = 0; ch < NCH; ++ch) M = fmaxf(M, pm[((size_t)b*NCH + ch)*128 + c]);
    float S = 0.0f;
    for (int ch = 0; ch < NCH; ++ch) {
        float m = pm[((size_t)b*NCH + ch)*128 + c];
        if (m > -INFINITY) S += ps[((size_t)b*NCH + ch)*128 + c] * expf(m - M);
    }
    Ms[b*128 + c] = M;
    Ss[b*128 + c] = S;
}

// stats (rescaling chunk-local partials) -> layernorm(256) -> linear 256->512
__global__ void final_kernel(const float* __restrict__ pcm, const float* __restrict__ pcq,
                             const float* __restrict__ pm,
                             const float* __restrict__ Ms, const float* __restrict__ Ss,
                             const float* __restrict__ gamma, const float* __restrict__ beta,
                             const float* __restrict__ w2, const float* __restrict__ b2,
                             float* __restrict__ out) {
    __shared__ float row[256];
    __shared__ float nrm[256];
    __shared__ float red[8];
    const int tid = threadIdx.x, b = blockIdx.x;
    if (tid < 128) {
        const float M = Ms[b*128 + tid];
        float sm = 0.0f, sq = 0.0f;
        for (int ch = 0; ch < NCH; ++ch) {
            size_t o = ((size_t)b*NCH + ch)*128 + tid;
            float m = pm[o];
            if (m > -INFINITY) {
                float e = expf(m - M);
                sm += pcm[o]*e;
                sq += pcq[o]*e;
            }
        }
        float S = Ss[b*128 + tid];
        float mean = sm / S;
        float q    = sq / S;
        float resid = q - mean*mean;
        float stdv  = sqrtf(fmaxf(resid, 1e-9f));
        row[tid]       = mean;
        row[128 + tid] = stdv;
    }
    __syncthreads();
    float v  = row[tid];
    float s1 = v, s2 = v*v;
    for (int off = 32; off >= 1; off >>= 1) {
        s1 += __shfl_down(s1, off, 64);
        s2 += __shfl_down(s2, off, 64);
    }
    if ((tid & 63) == 0) { red[tid >> 6] = s1; red[4 + (tid >> 6)] = s2; }
    __syncthreads();
    float S1 = red[0] + red[1] + red[2] + red[3];
    float S2 = red[4] + red[5] + red[6] + red[7];
    float mu  = S1 / 256.0f;
    float var = S2 / 256.0f - mu*mu;
    float inv = 1.0f / sqrtf(var + 1e-5f);
    nrm[tid] = (v - mu)*inv*gamma[tid] + beta[tid];
    __syncthreads();
#pragma unroll
    for (int oo = 0; oo < 2; ++oo) {
        int o = tid + oo*256;
        float acc = b2[o];
        const float4* wr = (const float4*)&w2[(size_t)o*256];
        for (int j = 0; j < 64; ++j) {
            float4 w = wr[j];
            acc += w.x*nrm[j*4] + w.y*nrm[j*4+1] + w.z*nrm[j*4+2] + w.w*nrm[j*4+3];
        }
        out[(size_t)b*512 + o] = acc;
    }
}

// ---------------------------------------------------------------------------
extern "C" void kernel_launch(void* const* d_in, const int* in_sizes, int n_in,
                              void* d_out, int out_size, void* d_ws, size_t ws_size,
                              hipStream_t stream) {
    const float* x      = (const float*)d_in[0];
    const float* bp     = (const float*)d_in[1];
    const float* w_lin1 = (const float*)d_in[2];
    const float* b_lin1 = (const float*)d_in[3];
    const float* wc1    = (const float*)d_in[4];
    const float* bc1    = (const float*)d_in[5];
    const float* wc2    = (const float*)d_in[6];
    const float* bc2    = (const float*)d_in[7];
    const float* wc3    = (const float*)d_in[8];
    const float* bc3    = (const float*)d_in[9];
    const float* wa1    = (const float*)d_in[10];
    const float* ba1    = (const float*)d_in[11];
    const float* wa2    = (const float*)d_in[12];
    const float* ba2    = (const float*)d_in[13];
    const float* gamma  = (const float*)d_in[14];
    const float* beta   = (const float*)d_in[15];
    const float* wl2    = (const float*)d_in[16];
    const float* bl2    = (const float*)d_in[17];

    float* ws   = (float*)d_ws;
    float* bs   = ws + OFF_BS;
    ushort_t* weh  = (ushort_t*)(ws + OFF_WEFF);
    ushort_t* wel  = weh + 64*320;
    float* wtail   = ws + OFF_WTAIL;
    ushort_t* w1h  = (ushort_t*)(ws + OFF_W1);
    ushort_t* w1l  = w1h + 3*128*64;
    ushort_t* w2h  = (ushort_t*)(ws + OFF_W2);
    ushort_t* w2l  = w2h + 3*128*128;
    ushort_t* w3h  = (ushort_t*)(ws + OFF_W3);
    ushort_t* w3l  = w3h + 3*128*128;
    ushort_t* wa1h = (ushort_t*)(ws + OFF_WA1);
    ushort_t* wa1l = wa1h + 64*128;
    ushort_t* wa2h = (ushort_t*)(ws + OFF_WA2);
    ushort_t* wa2l = wa2h + 128*64;
    float* pm   = ws + OFF_PM;
    float* ps   = ws + OFF_PS;
    float* Ms   = ws + OFF_MS;
    float* Ss   = ws + OFF_SS;
    float* pcm  = ws + OFF_PCM;
    float* pcq  = ws + OFF_PCQ;
    float* h    = ws + OFF_H;
    float* bufA = ws + OFF_A;    // i1, then i3
    float* bufB = ws + OFF_BB;   // s

    sort_kernel<<<dim3(1), dim3(64), 0, stream>>>(bp, bs);
    prep_kernel<<<dim3(624), dim3(256), 0, stream>>>(bs, w_lin1, wc1, wc2, wc3, wa1, wa2,
                                                     weh, wel, wtail, w1h, w1l, w2h, w2l,
                                                     w3h, w3l, wa1h, wa1l, wa2h, wa2l);
    // h = relu(x @ Weff^T + b_lin1)
    lin1_mfma<<<dim3(R_/128), dim3(256), 0, stream>>>(x, weh, wel, wtail, b_lin1, h);
    // i1 = conv1(h) + b
    dconv_mfma<64, 2, 0><<<dim3(47, B_), dim3(256), 0, stream>>>(h, w1h, w1l, bc1, bufA);
    // s = i1 + i2 = conv2(i1) + b + 2*i1
    dconv_mfma<128, 3, 2><<<dim3(47, B_), dim3(256), 0, stream>>>(bufA, w2h, w2l, bc2, bufB);
    // i3 = conv3(s) + b + s
    dconv_mfma<128, 4, 1><<<dim3(47, B_), dim3(256), 0, stream>>>(bufB, w3h, w3l, bc3, bufA);
    // fused asp1+asp2+softmax partials+weighted stats (no logits to HBM)
    asp_fused<<<dim3(NCH, B_), dim3(256), 0, stream>>>(bufA, wa1h, wa1l, wa2h, wa2l,
                                                       ba1, ba2, pm, ps, pcm, pcq);
    sm_pass_b<<<dim3(B_), dim3(128), 0, stream>>>(pm, ps, Ms, Ss);
    final_kernel<<<dim3(B_), dim3(256), 0, stream>>>(pcm, pcq, pm, Ms, Ss, gamma, beta,
                                                     wl2, bl2, (float*)d_out);
}